// Round 1
// baseline (2171.733 us; speedup 1.0000x reference)
//
#include <hip/hip_runtime.h>

#define N_NODES 100000
#define N_EDGES 1600000
#define IN_F 64
#define HID_F 64
#define OUT_F 32

// ---------- init agg buffers with broadcast bias ----------
__global__ void init_bias64(float* __restrict__ agg, const float* __restrict__ b) {
    int i = blockIdx.x * blockDim.x + threadIdx.x;  // over N_NODES*64
    if (i < N_NODES * 64) agg[i] = b[i & 63];
}

__global__ void init_bias32(float* __restrict__ out, const float* __restrict__ b) {
    int i = blockIdx.x * blockDim.x + threadIdx.x;  // over N_NODES*32
    if (i < N_NODES * 32) out[i] = b[i & 31];
}

// ---------- GEMM1: X1[N,64] = features[N,64] @ W1[64,64] ----------
__global__ __launch_bounds__(256) void gemm1(const float* __restrict__ X,
                                             const float* __restrict__ W,
                                             float* __restrict__ Y) {
    __shared__ float sW[64 * 64];
    __shared__ float sX[4][64];
    int t = threadIdx.x;
    for (int i = t; i < 64 * 64; i += 256) sW[i] = W[i];
    int r = t >> 6, c = t & 63;
    int row = blockIdx.x * 4 + r;
    if (row < N_NODES) sX[r][c] = X[row * 64 + c];
    __syncthreads();
    if (row < N_NODES) {
        float acc = 0.f;
#pragma unroll
        for (int k = 0; k < 64; k++) acc += sX[r][k] * sW[k * 64 + c];
        Y[row * 64 + c] = acc;
    }
}

// ---------- scatter layer 1: agg1[dst] += X1[src], 64 floats/edge ----------
__global__ __launch_bounds__(256) void scatter64(const float* __restrict__ X,
                                                 const int* __restrict__ src,
                                                 const int* __restrict__ dst,
                                                 float* __restrict__ agg) {
    long long gid = blockIdx.x * 256LL + threadIdx.x;  // E * 16 float4-chunks
    if (gid >= (long long)N_EDGES * 16) return;
    int e = (int)(gid >> 4);
    int c = (int)(gid & 15);
    int s = src[e], d = dst[e];
    const float4 v = ((const float4*)X)[s * 16 + c];
    float* p = agg + d * 64 + c * 4;
    unsafeAtomicAdd(p + 0, v.x);
    unsafeAtomicAdd(p + 1, v.y);
    unsafeAtomicAdd(p + 2, v.z);
    unsafeAtomicAdd(p + 3, v.w);
}

// ---------- fused: h2[N,32] = relu(agg1[N,64]) @ W2[64,32] ----------
__global__ __launch_bounds__(256) void gemm2_relu(const float* __restrict__ A,
                                                  const float* __restrict__ W,
                                                  float* __restrict__ Y) {
    __shared__ float sW[64 * 32];
    __shared__ float sX[8][64];
    int t = threadIdx.x;
    for (int i = t; i < 64 * 32; i += 256) sW[i] = W[i];
    int row0 = blockIdx.x * 8;
    for (int i = t; i < 8 * 64; i += 256) {
        int rr = i >> 6, cc = i & 63;
        int row = row0 + rr;
        float v = (row < N_NODES) ? A[row * 64 + cc] : 0.f;
        sX[rr][cc] = v > 0.f ? v : 0.f;
    }
    __syncthreads();
    int r = t >> 5, c = t & 31;
    int row = row0 + r;
    if (row < N_NODES) {
        float acc = 0.f;
#pragma unroll
        for (int k = 0; k < 64; k++) acc += sX[r][k] * sW[k * 32 + c];
        Y[row * 32 + c] = acc;
    }
}

// ---------- scatter layer 2: out[dst] += h2[src], 32 floats/edge ----------
__global__ __launch_bounds__(256) void scatter32(const float* __restrict__ X,
                                                 const int* __restrict__ src,
                                                 const int* __restrict__ dst,
                                                 float* __restrict__ out) {
    long long gid = blockIdx.x * 256LL + threadIdx.x;  // E * 8 float4-chunks
    if (gid >= (long long)N_EDGES * 8) return;
    int e = (int)(gid >> 3);
    int c = (int)(gid & 7);
    int s = src[e], d = dst[e];
    const float4 v = ((const float4*)X)[s * 8 + c];
    float* p = out + d * 32 + c * 4;
    unsafeAtomicAdd(p + 0, v.x);
    unsafeAtomicAdd(p + 1, v.y);
    unsafeAtomicAdd(p + 2, v.z);
    unsafeAtomicAdd(p + 3, v.w);
}

extern "C" void kernel_launch(void* const* d_in, const int* in_sizes, int n_in,
                              void* d_out, int out_size, void* d_ws, size_t ws_size,
                              hipStream_t stream) {
    const float* features = (const float*)d_in[0];
    const int*   src      = (const int*)d_in[1];
    const int*   dst      = (const int*)d_in[2];
    const float* W1       = (const float*)d_in[3];
    const float* b1       = (const float*)d_in[4];
    const float* W2       = (const float*)d_in[5];
    const float* b2       = (const float*)d_in[6];
    float* out = (float*)d_out;

    float* X1   = (float*)d_ws;               // N*64 floats (25.6 MB)
    float* agg1 = X1 + (size_t)N_NODES * 64;  // N*64 floats (25.6 MB)
    float* h2   = X1;                         // reuse X1 after scatter1

    // 1. X1 = features @ W1
    gemm1<<<(N_NODES + 3) / 4, 256, 0, stream>>>(features, W1, X1);
    // 2. agg1 = b1 (broadcast), then scatter-add
    init_bias64<<<(N_NODES * 64 + 255) / 256, 256, 0, stream>>>(agg1, b1);
    scatter64<<<(int)(((long long)N_EDGES * 16 + 255) / 256), 256, 0, stream>>>(X1, src, dst, agg1);
    // 3. h2 = relu(agg1) @ W2
    gemm2_relu<<<(N_NODES + 7) / 8, 256, 0, stream>>>(agg1, W2, h2);
    // 4. out = b2 (broadcast), then scatter-add
    init_bias32<<<(N_NODES * 32 + 255) / 256, 256, 0, stream>>>(out, b2);
    scatter32<<<(int)(((long long)N_EDGES * 8 + 255) / 256), 256, 0, stream>>>(h2, src, dst, out);
}

// Round 2
// 576.729 us; speedup vs baseline: 3.7656x; 3.7656x over previous
//
#include <hip/hip_runtime.h>

#define N_NODES 100000
#define N_EDGES 1600000

// ---------------- CSR build ----------------
__global__ void zero_deg(int* __restrict__ deg) {
    int i = blockIdx.x * 256 + threadIdx.x;
    if (i < N_NODES) deg[i] = 0;
}

__global__ void hist(const int* __restrict__ dst, int* __restrict__ deg) {
    int e = blockIdx.x * 256 + threadIdx.x;
    if (e < N_EDGES) atomicAdd(&deg[dst[e]], 1);
}

// Per-1024-chunk inclusive scan. 98 blocks x 256 threads x 4 elems.
__global__ __launch_bounds__(256) void scan1(const int* __restrict__ deg,
                                             int* __restrict__ incl,
                                             int* __restrict__ bsum) {
    __shared__ int sw[4];
    int t = threadIdx.x, lane = t & 63, wid = t >> 6;
    int base = blockIdx.x * 1024 + t * 4;
    int v0 = (base + 0 < N_NODES) ? deg[base + 0] : 0;
    int v1 = (base + 1 < N_NODES) ? deg[base + 1] : 0;
    int v2 = (base + 2 < N_NODES) ? deg[base + 2] : 0;
    int v3 = (base + 3 < N_NODES) ? deg[base + 3] : 0;
    int tsum = v0 + v1 + v2 + v3;
    int s = tsum;
    for (int o = 1; o < 64; o <<= 1) {
        int u = __shfl_up(s, o);
        if (lane >= o) s += u;
    }
    if (lane == 63) sw[wid] = s;
    __syncthreads();
    int wofs = 0;
    for (int w = 0; w < wid; w++) wofs += sw[w];
    int excl = wofs + s - tsum;
    int i0 = excl + v0, i1 = i0 + v1, i2 = i1 + v2, i3 = i2 + v3;
    if (base + 0 < N_NODES) incl[base + 0] = i0;
    if (base + 1 < N_NODES) incl[base + 1] = i1;
    if (base + 2 < N_NODES) incl[base + 2] = i2;
    if (base + 3 < N_NODES) incl[base + 3] = i3;
    if (t == 255) bsum[blockIdx.x] = wofs + s;
}

// Exclusive scan of 98 block sums in one 128-thread block.
__global__ void scan2(const int* __restrict__ bsum, int* __restrict__ boff) {
    __shared__ int tmp[128];
    int t = threadIdx.x;
    int mine = (t < 98) ? bsum[t] : 0;
    tmp[t] = mine;
    for (int o = 1; o < 128; o <<= 1) {
        __syncthreads();
        int v = (t >= o) ? tmp[t - o] : 0;
        __syncthreads();
        tmp[t] += v;
    }
    __syncthreads();
    if (t < 98) boff[t] = tmp[t] - mine;
}

// off[i] = global exclusive prefix; cursor[i] = copy for the fill pass.
__global__ void scan3(const int* __restrict__ incl, const int* __restrict__ boff,
                      int* __restrict__ off, int* __restrict__ cursor) {
    int i = blockIdx.x * 256 + threadIdx.x;
    if (i >= N_NODES) return;
    int e = boff[i >> 10] + ((i & 1023) ? incl[i - 1] : 0);
    off[i] = e;
    cursor[i] = e;
}

__global__ void fill(const int* __restrict__ src, const int* __restrict__ dst,
                     int* __restrict__ cursor, int* __restrict__ csr) {
    int e = blockIdx.x * 256 + threadIdx.x;
    if (e >= N_EDGES) return;
    int pos = atomicAdd(&cursor[dst[e]], 1);
    csr[pos] = src[e];
}

// ---------------- fused gather-sum + GEMM + bias (+relu) ----------------
// One wave per node; lane = input channel. acc[lane] = sum of X[src][lane].
// Then y[oc] = sum_k acc[k]*W[k][oc] + b[oc] via shfl-broadcast matvec.
template <int OUTF, bool RELU>
__global__ __launch_bounds__(256) void gather_gemm(
    const float* __restrict__ X, const int* __restrict__ off,
    const int* __restrict__ deg, const int* __restrict__ csr,
    const float* __restrict__ W, const float* __restrict__ b,
    float* __restrict__ Y) {
    __shared__ float sW[64 * OUTF];
    int t = threadIdx.x;
    for (int i = t; i < 64 * OUTF; i += 256) sW[i] = W[i];
    __syncthreads();
    int lane = t & 63, wid = t >> 6;
    int oc = lane & (OUTF - 1);
    float bias = b[oc];
    int w0 = blockIdx.x * 4 + wid, stride = gridDim.x * 4;
    for (int n = w0; n < N_NODES; n += stride) {
        int s0 = off[n], d = deg[n];
        float acc = 0.f;
        int j = 0;
        for (; j + 4 <= d; j += 4) {  // 4-way MLP on the dependent gather chain
            int sa = csr[s0 + j + 0], sb = csr[s0 + j + 1];
            int sc = csr[s0 + j + 2], sd = csr[s0 + j + 3];
            float xa = X[sa * 64 + lane], xb = X[sb * 64 + lane];
            float xc = X[sc * 64 + lane], xd = X[sd * 64 + lane];
            acc += xa + xb + xc + xd;
        }
        for (; j < d; j++) {
            int s = csr[s0 + j];
            acc += X[s * 64 + lane];
        }
        float y = bias;
#pragma unroll
        for (int k = 0; k < 64; k++) {
            float a = __shfl(acc, k);
            y += a * sW[k * OUTF + oc];
        }
        if (RELU) y = y > 0.f ? y : 0.f;
        if (lane < OUTF) Y[n * OUTF + lane] = y;
    }
}

extern "C" void kernel_launch(void* const* d_in, const int* in_sizes, int n_in,
                              void* d_out, int out_size, void* d_ws, size_t ws_size,
                              hipStream_t stream) {
    const float* features = (const float*)d_in[0];
    const int*   src      = (const int*)d_in[1];
    const int*   dst      = (const int*)d_in[2];
    const float* W1       = (const float*)d_in[3];
    const float* b1       = (const float*)d_in[4];
    const float* W2       = (const float*)d_in[5];
    const float* b2       = (const float*)d_in[6];
    float* out = (float*)d_out;

    // workspace layout (ints/floats, 256B-ish aligned by construction)
    char* p = (char*)d_ws;
    int* deg    = (int*)p;                 p += ((size_t)N_NODES * 4 + 255) / 256 * 256;
    int* off    = (int*)p;                 p += ((size_t)N_NODES * 4 + 255) / 256 * 256;
    int* cursor = (int*)p;                 p += ((size_t)N_NODES * 4 + 255) / 256 * 256;
    int* incl   = (int*)p;                 p += ((size_t)N_NODES * 4 + 255) / 256 * 256;
    int* bsum   = (int*)p;                 p += 512;
    int* boff   = (int*)p;                 p += 512;
    int* csr    = (int*)p;                 p += (size_t)N_EDGES * 4;
    float* h1   = (float*)p;               // N_NODES*64 floats (25.6 MB)

    // CSR build (shared by both layers)
    zero_deg<<<(N_NODES + 255) / 256, 256, 0, stream>>>(deg);
    hist<<<(N_EDGES + 255) / 256, 256, 0, stream>>>(dst, deg);
    scan1<<<98, 256, 0, stream>>>(deg, incl, bsum);
    scan2<<<1, 128, 0, stream>>>(bsum, boff);
    scan3<<<(N_NODES + 255) / 256, 256, 0, stream>>>(incl, boff, off, cursor);
    fill<<<(N_EDGES + 255) / 256, 256, 0, stream>>>(src, dst, cursor, csr);

    // layer 1: h1 = relu(segsum(features[src]) @ W1 + b1)
    gather_gemm<64, true><<<2048, 256, 0, stream>>>(features, off, deg, csr, W1, b1, h1);
    // layer 2: out = segsum(h1[src]) @ W2 + b2
    gather_gemm<32, false><<<2048, 256, 0, stream>>>(h1, off, deg, csr, W2, b2, out);
}

// Round 3
// 522.504 us; speedup vs baseline: 4.1564x; 1.1038x over previous
//
#include <hip/hip_runtime.h>

#define N_NODES 100000
#define N_EDGES 1600000

// ---------------- CSR build ----------------
__global__ void zero_deg(int* __restrict__ deg) {
    int i = blockIdx.x * 256 + threadIdx.x;
    if (i < N_NODES) deg[i] = 0;
}

__global__ void hist(const int* __restrict__ dst, int* __restrict__ deg) {
    int e = blockIdx.x * 256 + threadIdx.x;
    if (e < N_EDGES) atomicAdd(&deg[dst[e]], 1);
}

// Per-1024-chunk inclusive scan. 98 blocks x 256 threads x 4 elems.
__global__ __launch_bounds__(256) void scan1(const int* __restrict__ deg,
                                             int* __restrict__ incl,
                                             int* __restrict__ bsum) {
    __shared__ int sw[4];
    int t = threadIdx.x, lane = t & 63, wid = t >> 6;
    int base = blockIdx.x * 1024 + t * 4;
    int v0 = (base + 0 < N_NODES) ? deg[base + 0] : 0;
    int v1 = (base + 1 < N_NODES) ? deg[base + 1] : 0;
    int v2 = (base + 2 < N_NODES) ? deg[base + 2] : 0;
    int v3 = (base + 3 < N_NODES) ? deg[base + 3] : 0;
    int tsum = v0 + v1 + v2 + v3;
    int s = tsum;
    for (int o = 1; o < 64; o <<= 1) {
        int u = __shfl_up(s, o);
        if (lane >= o) s += u;
    }
    if (lane == 63) sw[wid] = s;
    __syncthreads();
    int wofs = 0;
    for (int w = 0; w < wid; w++) wofs += sw[w];
    int excl = wofs + s - tsum;
    int i0 = excl + v0, i1 = i0 + v1, i2 = i1 + v2, i3 = i2 + v3;
    if (base + 0 < N_NODES) incl[base + 0] = i0;
    if (base + 1 < N_NODES) incl[base + 1] = i1;
    if (base + 2 < N_NODES) incl[base + 2] = i2;
    if (base + 3 < N_NODES) incl[base + 3] = i3;
    if (t == 255) bsum[blockIdx.x] = wofs + s;
}

// Exclusive scan of 98 block sums in one 128-thread block.
__global__ void scan2(const int* __restrict__ bsum, int* __restrict__ boff) {
    __shared__ int tmp[128];
    int t = threadIdx.x;
    int mine = (t < 98) ? bsum[t] : 0;
    tmp[t] = mine;
    for (int o = 1; o < 128; o <<= 1) {
        __syncthreads();
        int v = (t >= o) ? tmp[t - o] : 0;
        __syncthreads();
        tmp[t] += v;
    }
    __syncthreads();
    if (t < 98) boff[t] = tmp[t] - mine;
}

__global__ void scan3(const int* __restrict__ incl, const int* __restrict__ boff,
                      int* __restrict__ off, int* __restrict__ cursor) {
    int i = blockIdx.x * 256 + threadIdx.x;
    if (i >= N_NODES) return;
    int e = boff[i >> 10] + ((i & 1023) ? incl[i - 1] : 0);
    off[i] = e;
    cursor[i] = e;
}

__global__ void fill(const int* __restrict__ src, const int* __restrict__ dst,
                     int* __restrict__ cursor, int* __restrict__ csr) {
    int e = blockIdx.x * 256 + threadIdx.x;
    if (e >= N_EDGES) return;
    int pos = atomicAdd(&cursor[dst[e]], 1);
    csr[pos] = src[e];
}

// ---------------- layer 1 fused ----------------
// One wave per node. Quarter-wave gather: group g=lane>>4 takes edges j≡g (mod 4),
// lane covers 4 channels via float4. Reduce across groups with shfl_xor, then
// shfl-broadcast matvec: y = relu(agg@W1+b1), z = y@W2. Write z (N x 32).
__global__ __launch_bounds__(256) void layer1(
    const float4* __restrict__ X4, const int* __restrict__ off,
    const int* __restrict__ deg, const int* __restrict__ csr,
    const float* __restrict__ W1, const float* __restrict__ b1,
    const float* __restrict__ W2, float* __restrict__ Z) {
    __shared__ float sW1[64 * 64];
    __shared__ float sW2[64 * 32];
    int t = threadIdx.x;
    for (int i = t; i < 64 * 64; i += 256) sW1[i] = W1[i];
    for (int i = t; i < 64 * 32; i += 256) sW2[i] = W2[i];
    __syncthreads();
    int lane = t & 63, wid = t >> 6;
    int il = lane & 15, g = lane >> 4;
    float bias = b1[lane];
    int w0 = blockIdx.x * 4 + wid, stride = gridDim.x * 4;
    for (int n = w0; n < N_NODES; n += stride) {
        int s0 = off[n], d = deg[n];
        float4 acc = {0.f, 0.f, 0.f, 0.f};
        int j = g;
        for (; j + 4 < d; j += 8) {  // two rows in flight per group
            int sa = csr[s0 + j], sb = csr[s0 + j + 4];
            float4 va = X4[sa * 16 + il];
            float4 vb = X4[sb * 16 + il];
            acc.x += va.x + vb.x; acc.y += va.y + vb.y;
            acc.z += va.z + vb.z; acc.w += va.w + vb.w;
        }
        if (j < d) {
            int sa = csr[s0 + j];
            float4 va = X4[sa * 16 + il];
            acc.x += va.x; acc.y += va.y; acc.z += va.z; acc.w += va.w;
        }
#pragma unroll
        for (int m = 16; m < 64; m <<= 1) {
            acc.x += __shfl_xor(acc.x, m);
            acc.y += __shfl_xor(acc.y, m);
            acc.z += __shfl_xor(acc.z, m);
            acc.w += __shfl_xor(acc.w, m);
        }
        // lane (any group) with index il holds channels 4*il..4*il+3 in acc
        float y = bias;
#pragma unroll
        for (int k = 0; k < 64; k++) {
            float a;
            switch (k & 3) {
                case 0: a = __shfl(acc.x, k >> 2); break;
                case 1: a = __shfl(acc.y, k >> 2); break;
                case 2: a = __shfl(acc.z, k >> 2); break;
                default: a = __shfl(acc.w, k >> 2); break;
            }
            y += a * sW1[k * 64 + lane];
        }
        y = y > 0.f ? y : 0.f;
        int oc = lane & 31;
        float z = 0.f;
#pragma unroll
        for (int k = 0; k < 64; k++) {
            float a = __shfl(y, k);
            z += a * sW2[k * 32 + oc];
        }
        if (lane < 32) Z[n * 32 + lane] = z;
    }
}

// ---------------- layer 2: pure gather-sum of 32-float rows + bias ----------------
// Octet-wave gather: group g=lane>>3 takes edges j≡g (mod 8), lane covers 4
// channels via float4 (il=lane&7). Reduce across 8 groups, add b2, store.
__global__ __launch_bounds__(256) void layer2(
    const float4* __restrict__ Z4, const int* __restrict__ off,
    const int* __restrict__ deg, const int* __restrict__ csr,
    const float* __restrict__ b2, float4* __restrict__ out4) {
    int t = threadIdx.x;
    int lane = t & 63, wid = t >> 6;
    int il = lane & 7, g = lane >> 3;
    const float4 bb = ((const float4*)b2)[il];
    int w0 = blockIdx.x * 4 + wid, stride = gridDim.x * 4;
    for (int n = w0; n < N_NODES; n += stride) {
        int s0 = off[n], d = deg[n];
        float4 acc = {0.f, 0.f, 0.f, 0.f};
        int j = g;
        for (; j + 8 < d; j += 16) {
            int sa = csr[s0 + j], sb = csr[s0 + j + 8];
            float4 va = Z4[sa * 8 + il];
            float4 vb = Z4[sb * 8 + il];
            acc.x += va.x + vb.x; acc.y += va.y + vb.y;
            acc.z += va.z + vb.z; acc.w += va.w + vb.w;
        }
        if (j < d) {
            int sa = csr[s0 + j];
            float4 va = Z4[sa * 8 + il];
            acc.x += va.x; acc.y += va.y; acc.z += va.z; acc.w += va.w;
        }
#pragma unroll
        for (int m = 8; m < 64; m <<= 1) {
            acc.x += __shfl_xor(acc.x, m);
            acc.y += __shfl_xor(acc.y, m);
            acc.z += __shfl_xor(acc.z, m);
            acc.w += __shfl_xor(acc.w, m);
        }
        acc.x += bb.x; acc.y += bb.y; acc.z += bb.z; acc.w += bb.w;
        if (lane < 8) out4[n * 8 + lane] = acc;
    }
}

extern "C" void kernel_launch(void* const* d_in, const int* in_sizes, int n_in,
                              void* d_out, int out_size, void* d_ws, size_t ws_size,
                              hipStream_t stream) {
    const float* features = (const float*)d_in[0];
    const int*   src      = (const int*)d_in[1];
    const int*   dst      = (const int*)d_in[2];
    const float* W1       = (const float*)d_in[3];
    const float* b1       = (const float*)d_in[4];
    const float* W2       = (const float*)d_in[5];
    const float* b2       = (const float*)d_in[6];
    float* out = (float*)d_out;

    char* p = (char*)d_ws;
    int* deg    = (int*)p;                 p += ((size_t)N_NODES * 4 + 255) / 256 * 256;
    int* off    = (int*)p;                 p += ((size_t)N_NODES * 4 + 255) / 256 * 256;
    int* cursor = (int*)p;                 p += ((size_t)N_NODES * 4 + 255) / 256 * 256;
    int* incl   = (int*)p;                 p += ((size_t)N_NODES * 4 + 255) / 256 * 256;
    int* bsum   = (int*)p;                 p += 512;
    int* boff   = (int*)p;                 p += 512;
    int* csr    = (int*)p;                 p += (size_t)N_EDGES * 4;
    float* Z    = (float*)p;               // N_NODES*32 floats (12.8 MB)

    zero_deg<<<(N_NODES + 255) / 256, 256, 0, stream>>>(deg);
    hist<<<(N_EDGES + 255) / 256, 256, 0, stream>>>(dst, deg);
    scan1<<<98, 256, 0, stream>>>(deg, incl, bsum);
    scan2<<<1, 128, 0, stream>>>(bsum, boff);
    scan3<<<(N_NODES + 255) / 256, 256, 0, stream>>>(incl, boff, off, cursor);
    fill<<<(N_EDGES + 255) / 256, 256, 0, stream>>>(src, dst, cursor, csr);

    layer1<<<2048, 256, 0, stream>>>((const float4*)features, off, deg, csr, W1, b1, W2, Z);
    layer2<<<2048, 256, 0, stream>>>((const float4*)Z, off, deg, csr, b2, (float4*)out);
}

// Round 4
// 356.010 us; speedup vs baseline: 6.1002x; 1.4677x over previous
//
#include <hip/hip_runtime.h>

#define N_NODES 100000
#define N_EDGES 1600000
#define YP 72  // padded LDS row (bf16 elems): 2-way-max bank aliasing, 16B aligned

typedef __attribute__((ext_vector_type(8))) short bhalf8;
typedef __attribute__((ext_vector_type(4))) float f32x4;

__device__ __forceinline__ unsigned short bf16r(float f) {
    unsigned u = __float_as_uint(f);
    unsigned r = (u >> 16) & 1;
    return (unsigned short)((u + 0x7fffu + r) >> 16);
}
__device__ __forceinline__ unsigned pk2(float a, float b) {
    return (unsigned)bf16r(a) | ((unsigned)bf16r(b) << 16);
}
__device__ __forceinline__ float bl(unsigned u) { return __uint_as_float(u << 16); }
__device__ __forceinline__ float bh(unsigned u) { return __uint_as_float(u & 0xffff0000u); }

// ---------------- prepass: features -> bf16, zero deg ----------------
__global__ void convert_zero(const float4* __restrict__ X4, uint2* __restrict__ Xb,
                             int* __restrict__ deg) {
    int i = blockIdx.x * 256 + threadIdx.x;  // over N*16 float4 chunks
    if (i < N_NODES * 16) {
        float4 v = X4[i];
        uint2 o; o.x = pk2(v.x, v.y); o.y = pk2(v.z, v.w);
        Xb[i] = o;
    }
    if (i < N_NODES) deg[i] = 0;
}

// ---------------- CSR build ----------------
__global__ void hist(const int* __restrict__ dst, int* __restrict__ deg) {
    int e = blockIdx.x * 256 + threadIdx.x;
    if (e < N_EDGES) atomicAdd(&deg[dst[e]], 1);
}

__global__ __launch_bounds__(256) void scan1(const int* __restrict__ deg,
                                             int* __restrict__ incl,
                                             int* __restrict__ bsum) {
    __shared__ int sw[4];
    int t = threadIdx.x, lane = t & 63, wid = t >> 6;
    int base = blockIdx.x * 1024 + t * 4;
    int v0 = (base + 0 < N_NODES) ? deg[base + 0] : 0;
    int v1 = (base + 1 < N_NODES) ? deg[base + 1] : 0;
    int v2 = (base + 2 < N_NODES) ? deg[base + 2] : 0;
    int v3 = (base + 3 < N_NODES) ? deg[base + 3] : 0;
    int tsum = v0 + v1 + v2 + v3;
    int s = tsum;
    for (int o = 1; o < 64; o <<= 1) {
        int u = __shfl_up(s, o);
        if (lane >= o) s += u;
    }
    if (lane == 63) sw[wid] = s;
    __syncthreads();
    int wofs = 0;
    for (int w = 0; w < wid; w++) wofs += sw[w];
    int excl = wofs + s - tsum;
    int i0 = excl + v0, i1 = i0 + v1, i2 = i1 + v2, i3 = i2 + v3;
    if (base + 0 < N_NODES) incl[base + 0] = i0;
    if (base + 1 < N_NODES) incl[base + 1] = i1;
    if (base + 2 < N_NODES) incl[base + 2] = i2;
    if (base + 3 < N_NODES) incl[base + 3] = i3;
    if (t == 255) bsum[blockIdx.x] = wofs + s;
}

__global__ void scan2(const int* __restrict__ bsum, int* __restrict__ boff) {
    __shared__ int tmp[128];
    int t = threadIdx.x;
    int mine = (t < 98) ? bsum[t] : 0;
    tmp[t] = mine;
    for (int o = 1; o < 128; o <<= 1) {
        __syncthreads();
        int v = (t >= o) ? tmp[t - o] : 0;
        __syncthreads();
        tmp[t] += v;
    }
    __syncthreads();
    if (t < 98) boff[t] = tmp[t] - mine;
}

__global__ void scan3(const int* __restrict__ incl, const int* __restrict__ boff,
                      int* __restrict__ off, int* __restrict__ cursor) {
    int i = blockIdx.x * 256 + threadIdx.x;
    if (i >= N_NODES) return;
    int e = boff[i >> 10] + ((i & 1023) ? incl[i - 1] : 0);
    off[i] = e;
    cursor[i] = e;
}

__global__ void fill(const int* __restrict__ src, const int* __restrict__ dst,
                     int* __restrict__ cursor, int* __restrict__ csr) {
    int e = blockIdx.x * 256 + threadIdx.x;
    if (e >= N_EDGES) return;
    int pos = atomicAdd(&cursor[dst[e]], 1);
    csr[pos] = src[e];
}

// ---------------- gather 1: aggb[n] = sum Xb[src] (bf16 in, fp32 acc, bf16 out) ----
// Quarter-wave groups: g=lane>>4 takes edges j≡g (mod 4); lane covers channels
// 4il..4il+3 via one uint2 (8B) load per row. Unroll 4 -> 16 rows in flight/wave.
__global__ __launch_bounds__(256) void gather1(
    const uint2* __restrict__ Xb, const int* __restrict__ off,
    const int* __restrict__ deg, const int* __restrict__ csr,
    uint2* __restrict__ aggb) {
    int t = threadIdx.x, lane = t & 63, wid = t >> 6;
    int il = lane & 15, g = lane >> 4;
    int w0 = blockIdx.x * 4 + wid, stride = gridDim.x * 4;
    for (int n = w0; n < N_NODES; n += stride) {
        int s0 = off[n], d = deg[n];
        float ax = 0.f, ay = 0.f, az = 0.f, aw = 0.f;
        int j = g;
        for (; j + 12 < d; j += 16) {
            int sa = csr[s0 + j], sb = csr[s0 + j + 4];
            int sc = csr[s0 + j + 8], sd = csr[s0 + j + 12];
            uint2 va = Xb[sa * 16 + il], vb = Xb[sb * 16 + il];
            uint2 vc = Xb[sc * 16 + il], vd = Xb[sd * 16 + il];
            ax += bl(va.x) + bl(vb.x) + bl(vc.x) + bl(vd.x);
            ay += bh(va.x) + bh(vb.x) + bh(vc.x) + bh(vd.x);
            az += bl(va.y) + bl(vb.y) + bl(vc.y) + bl(vd.y);
            aw += bh(va.y) + bh(vb.y) + bh(vc.y) + bh(vd.y);
        }
        for (; j < d; j += 4) {
            int sa = csr[s0 + j];
            uint2 va = Xb[sa * 16 + il];
            ax += bl(va.x); ay += bh(va.x); az += bl(va.y); aw += bh(va.y);
        }
#pragma unroll
        for (int m = 16; m < 64; m <<= 1) {
            ax += __shfl_xor(ax, m); ay += __shfl_xor(ay, m);
            az += __shfl_xor(az, m); aw += __shfl_xor(aw, m);
        }
        if (g == 0) {
            uint2 o; o.x = pk2(ax, ay); o.y = pk2(az, aw);
            aggb[n * 16 + il] = o;
        }
    }
}

// ---------------- gemm12: Zb = relu(aggb @ W1 + b1) @ W2  (MFMA, bf16) --------
// Transposed orientation: D1 = W1^T(64x64) . agg^T(64x16-nodes) -> y^T[h][node];
// C-layout col = node so stores/loads stay row-contiguous per node.
__global__ __launch_bounds__(256) void gemm12(
    const unsigned short* __restrict__ aggb,  // N x 64 bf16
    const float* __restrict__ W1, const float* __restrict__ b1,
    const float* __restrict__ W2,
    unsigned short* __restrict__ Zb) {        // N x 32 bf16
    __shared__ unsigned short sW1t[64 * YP];  // W1^T: [h][k]
    __shared__ unsigned short sW2t[32 * YP];  // W2^T: [oc][h]
    __shared__ unsigned short sy[4][16 * YP]; // per-wave y tile [node][h]
    int t = threadIdx.x;
    for (int i = t; i < 64 * 64; i += 256) {
        int k = i >> 6, h = i & 63;
        sW1t[h * YP + k] = bf16r(W1[k * 64 + h]);
    }
    for (int i = t; i < 64 * 32; i += 256) {
        int k = i >> 5, oc = i & 31;
        sW2t[oc * YP + k] = bf16r(W2[k * 32 + oc]);
    }
    __syncthreads();
    int lane = t & 63, wid = t >> 6;
    int m = lane & 15, quad = lane >> 4;
    // hoist all W fragments into registers (reused for every node block)
    bhalf8 A1[4][2], A2[2][2];
#pragma unroll
    for (int tile = 0; tile < 4; tile++)
#pragma unroll
        for (int c = 0; c < 2; c++)
            A1[tile][c] = *(const bhalf8*)&sW1t[(tile * 16 + m) * YP + c * 32 + quad * 8];
#pragma unroll
    for (int tile = 0; tile < 2; tile++)
#pragma unroll
        for (int c = 0; c < 2; c++)
            A2[tile][c] = *(const bhalf8*)&sW2t[(tile * 16 + m) * YP + c * 32 + quad * 8];
    f32x4 bias1[4];
#pragma unroll
    for (int tile = 0; tile < 4; tile++)
#pragma unroll
        for (int r = 0; r < 4; r++) bias1[tile][r] = b1[tile * 16 + quad * 4 + r];

    unsigned short* yt = sy[wid];
    int nb0 = blockIdx.x * 4 + wid, nstride = gridDim.x * 4;
    for (int nb = nb0; nb < N_NODES / 16; nb += nstride) {
        int node = nb * 16 + m;
        const unsigned short* arow = aggb + (size_t)node * 64;
        bhalf8 Bc0 = *(const bhalf8*)(arow + quad * 8);
        bhalf8 Bc1 = *(const bhalf8*)(arow + 32 + quad * 8);
#pragma unroll
        for (int tile = 0; tile < 4; tile++) {
            f32x4 a = bias1[tile];
            a = __builtin_amdgcn_mfma_f32_16x16x32_bf16(A1[tile][0], Bc0, a, 0, 0, 0);
            a = __builtin_amdgcn_mfma_f32_16x16x32_bf16(A1[tile][1], Bc1, a, 0, 0, 0);
            float y0 = a[0] > 0.f ? a[0] : 0.f, y1 = a[1] > 0.f ? a[1] : 0.f;
            float y2 = a[2] > 0.f ? a[2] : 0.f, y3 = a[3] > 0.f ? a[3] : 0.f;
            uint2 o; o.x = pk2(y0, y1); o.y = pk2(y2, y3);
            *(uint2*)&yt[m * YP + tile * 16 + quad * 4] = o;  // y[node][h..h+3]
        }
        bhalf8 Y0 = *(const bhalf8*)&yt[m * YP + quad * 8];
        bhalf8 Y1 = *(const bhalf8*)&yt[m * YP + 32 + quad * 8];
#pragma unroll
        for (int tile = 0; tile < 2; tile++) {
            f32x4 z = {0.f, 0.f, 0.f, 0.f};
            z = __builtin_amdgcn_mfma_f32_16x16x32_bf16(A2[tile][0], Y0, z, 0, 0, 0);
            z = __builtin_amdgcn_mfma_f32_16x16x32_bf16(A2[tile][1], Y1, z, 0, 0, 0);
            uint2 o; o.x = pk2(z[0], z[1]); o.y = pk2(z[2], z[3]);
            *(uint2*)&Zb[(size_t)node * 32 + tile * 16 + quad * 4] = o;
        }
    }
}

// ---------------- gather 2: out[n] = sum Zb[src] + b2 (fp32 out) ----------------
__global__ __launch_bounds__(256) void gather2(
    const unsigned* __restrict__ Zb, const int* __restrict__ off,
    const int* __restrict__ deg, const int* __restrict__ csr,
    const float* __restrict__ b2, float2* __restrict__ out) {
    int t = threadIdx.x, lane = t & 63, wid = t >> 6;
    int il = lane & 15, g = lane >> 4;
    float2 bb = ((const float2*)b2)[il];
    int w0 = blockIdx.x * 4 + wid, stride = gridDim.x * 4;
    for (int n = w0; n < N_NODES; n += stride) {
        int s0 = off[n], d = deg[n];
        float ax = 0.f, ay = 0.f;
        int j = g;
        for (; j + 12 < d; j += 16) {
            int sa = csr[s0 + j], sb = csr[s0 + j + 4];
            int sc = csr[s0 + j + 8], sd = csr[s0 + j + 12];
            unsigned ua = Zb[sa * 16 + il], ub = Zb[sb * 16 + il];
            unsigned uc = Zb[sc * 16 + il], ud = Zb[sd * 16 + il];
            ax += bl(ua) + bl(ub) + bl(uc) + bl(ud);
            ay += bh(ua) + bh(ub) + bh(uc) + bh(ud);
        }
        for (; j < d; j += 4) {
            int sa = csr[s0 + j];
            unsigned ua = Zb[sa * 16 + il];
            ax += bl(ua); ay += bh(ua);
        }
#pragma unroll
        for (int m = 16; m < 64; m <<= 1) {
            ax += __shfl_xor(ax, m); ay += __shfl_xor(ay, m);
        }
        if (g == 0) {
            float2 o; o.x = ax + bb.x; o.y = ay + bb.y;
            out[n * 16 + il] = o;
        }
    }
}

extern "C" void kernel_launch(void* const* d_in, const int* in_sizes, int n_in,
                              void* d_out, int out_size, void* d_ws, size_t ws_size,
                              hipStream_t stream) {
    const float* features = (const float*)d_in[0];
    const int*   src      = (const int*)d_in[1];
    const int*   dst      = (const int*)d_in[2];
    const float* W1       = (const float*)d_in[3];
    const float* b1       = (const float*)d_in[4];
    const float* W2       = (const float*)d_in[5];
    const float* b2       = (const float*)d_in[6];

    char* p = (char*)d_ws;
    int* deg    = (int*)p;  p += ((size_t)N_NODES * 4 + 255) / 256 * 256;
    int* off    = (int*)p;  p += ((size_t)N_NODES * 4 + 255) / 256 * 256;
    int* cursor = (int*)p;  p += ((size_t)N_NODES * 4 + 255) / 256 * 256;
    int* incl   = (int*)p;  p += ((size_t)N_NODES * 4 + 255) / 256 * 256;
    int* bsum   = (int*)p;  p += 512;
    int* boff   = (int*)p;  p += 512;
    int* csr    = (int*)p;  p += (size_t)N_EDGES * 4;
    uint2* Xb   = (uint2*)p;          p += (size_t)N_NODES * 64 * 2;  // bf16 feats
    unsigned short* aggb = (unsigned short*)p; p += (size_t)N_NODES * 64 * 2;
    unsigned short* Zb   = (unsigned short*)p; p += (size_t)N_NODES * 32 * 2;

    convert_zero<<<(N_NODES * 16 + 255) / 256, 256, 0, stream>>>((const float4*)features, Xb, deg);
    hist<<<(N_EDGES + 255) / 256, 256, 0, stream>>>(dst, deg);
    scan1<<<98, 256, 0, stream>>>(deg, incl, bsum);
    scan2<<<1, 128, 0, stream>>>(bsum, boff);
    scan3<<<(N_NODES + 255) / 256, 256, 0, stream>>>(incl, boff, off, cursor);
    fill<<<(N_EDGES + 255) / 256, 256, 0, stream>>>(src, dst, cursor, csr);

    gather1<<<2048, 256, 0, stream>>>(Xb, off, deg, csr, (uint2*)aggb);
    gemm12<<<256, 256, 0, stream>>>(aggb, W1, b1, W2, Zb);
    gather2<<<2048, 256, 0, stream>>>((const unsigned*)Zb, off, deg, csr, b2, (float2*)d_out);
}

// Round 5
// 218.120 us; speedup vs baseline: 9.9566x; 1.6322x over previous
//
#include <hip/hip_runtime.h>

#define N_NODES 100000
#define N_EDGES 1600000
#define NB 782    // ceil(N_NODES/128) buckets of 128 dst-nodes
#define BCAP 4096 // LDS staging capacity per bucket (mean 2046, sigma 45 -> 45-sigma safe)
#define YP 72     // padded LDS row (bf16 elems) for gemm12

typedef __attribute__((ext_vector_type(8))) short bhalf8;
typedef __attribute__((ext_vector_type(4))) float f32x4;

__device__ __forceinline__ unsigned short bf16r(float f) {
    unsigned u = __float_as_uint(f);
    unsigned r = (u >> 16) & 1;
    return (unsigned short)((u + 0x7fffu + r) >> 16);
}
__device__ __forceinline__ unsigned pk2(float a, float b) {
    return (unsigned)bf16r(a) | ((unsigned)bf16r(b) << 16);
}
__device__ __forceinline__ float bl(unsigned u) { return __uint_as_float(u << 16); }
__device__ __forceinline__ float bh(unsigned u) { return __uint_as_float(u & 0xffff0000u); }

// ---------------- prepass: features -> bf16, zero bucket totals ----------------
__global__ void convert_zero(const float4* __restrict__ X4, uint2* __restrict__ Xb,
                             int* __restrict__ btot) {
    int i = blockIdx.x * 256 + threadIdx.x;
    if (i < N_NODES * 16) {
        float4 v = X4[i];
        uint2 o; o.x = pk2(v.x, v.y); o.y = pk2(v.z, v.w);
        Xb[i] = o;
    }
    if (i < NB) btot[i] = 0;
}

// ---------------- pass0: bucket histogram (LDS-aggregated) ----------------
__global__ __launch_bounds__(256) void pass0(const int* __restrict__ dst,
                                             int* __restrict__ btot) {
    __shared__ int h[NB];
    int t = threadIdx.x;
    for (int b = t; b < NB; b += 256) h[b] = 0;
    __syncthreads();
    int e0 = blockIdx.x * 4096 + t;
#pragma unroll
    for (int i = 0; i < 16; i++) {
        int e = e0 + i * 256;
        if (e < N_EDGES) atomicAdd(&h[dst[e] >> 7], 1);
    }
    __syncthreads();
    for (int b = t; b < NB; b += 256)
        if (h[b]) atomicAdd(&btot[b], h[b]);
}

// ---------------- scanB: exclusive scan of bucket totals (1 block) ----------------
__global__ __launch_bounds__(256) void scanB(const int* __restrict__ btot,
                                             int* __restrict__ bbase,
                                             int* __restrict__ gcur) {
    __shared__ int sw[4];
    int t = threadIdx.x, lane = t & 63, wid = t >> 6;
    int base = t * 4;
    int v0 = (base + 0 < NB) ? btot[base + 0] : 0;
    int v1 = (base + 1 < NB) ? btot[base + 1] : 0;
    int v2 = (base + 2 < NB) ? btot[base + 2] : 0;
    int v3 = (base + 3 < NB) ? btot[base + 3] : 0;
    int tsum = v0 + v1 + v2 + v3;
    int s = tsum;
    for (int o = 1; o < 64; o <<= 1) {
        int u = __shfl_up(s, o);
        if (lane >= o) s += u;
    }
    if (lane == 63) sw[wid] = s;
    __syncthreads();
    int wofs = 0;
    for (int w = 0; w < wid; w++) wofs += sw[w];
    int excl = wofs + s - tsum;
    int e0 = excl, e1 = e0 + v0, e2 = e1 + v1, e3 = e2 + v2;
    if (base + 0 < NB) { bbase[base + 0] = e0; gcur[base + 0] = e0; }
    if (base + 1 < NB) { bbase[base + 1] = e1; gcur[base + 1] = e1; }
    if (base + 2 < NB) { bbase[base + 2] = e2; gcur[base + 2] = e2; }
    if (base + 3 < NB) { bbase[base + 3] = e3; gcur[base + 3] = e3; }
    if (t == 0) bbase[NB] = N_EDGES;
}

// ---------------- pass1: scatter packed (src<<7|dstlocal) into bucket regions ----
__global__ __launch_bounds__(256) void pass1(const int* __restrict__ src,
                                             const int* __restrict__ dst,
                                             int* __restrict__ gcur,
                                             unsigned* __restrict__ ebuf) {
    __shared__ int h[NB];
    __shared__ int cur[NB];
    int t = threadIdx.x;
    for (int b = t; b < NB; b += 256) h[b] = 0;
    __syncthreads();
    int e0 = blockIdx.x * 4096 + t;
    unsigned pk[16]; int bk[16];
#pragma unroll
    for (int i = 0; i < 16; i++) {
        int e = e0 + i * 256;
        if (e < N_EDGES) {
            int s = src[e], d = dst[e];
            bk[i] = d >> 7;
            pk[i] = ((unsigned)s << 7) | (unsigned)(d & 127);
            atomicAdd(&h[bk[i]], 1);
        } else bk[i] = -1;
    }
    __syncthreads();
    for (int b = t; b < NB; b += 256)
        cur[b] = h[b] ? atomicAdd(&gcur[b], h[b]) : 0;
    __syncthreads();
#pragma unroll
    for (int i = 0; i < 16; i++)
        if (bk[i] >= 0) {
            int r = atomicAdd(&cur[bk[i]], 1);
            ebuf[r] = pk[i];
        }
}

// ---------------- pass2: per-bucket node offsets + coalesced CSR write ----------
__global__ __launch_bounds__(256) void pass2(const unsigned* __restrict__ ebuf,
                                             const int* __restrict__ bbase,
                                             int* __restrict__ off,
                                             int* __restrict__ deg,
                                             int* __restrict__ csr) {
    __shared__ int hh[128], sc[128];
    __shared__ int stg[BCAP];
    int b = blockIdx.x, t = threadIdx.x;
    int base = bbase[b], cnt = bbase[b + 1] - base;
    if (t < 128) hh[t] = 0;
    __syncthreads();
    for (int i = t; i < cnt; i += 256) atomicAdd(&hh[ebuf[base + i] & 127], 1);
    __syncthreads();
    if (t == 0) { int a = 0; for (int k = 0; k < 128; k++) { sc[k] = a; a += hh[k]; } }
    __syncthreads();
    if (t < 128) {
        int n = b * 128 + t;
        if (n < N_NODES) { off[n] = base + sc[t]; deg[n] = hh[t]; }
    }
    __syncthreads();
    if (cnt <= BCAP) {
        for (int i = t; i < cnt; i += 256) {
            unsigned v = ebuf[base + i];
            int r = atomicAdd(&sc[v & 127], 1);
            stg[r] = (int)(v >> 7);
        }
        __syncthreads();
        for (int i = t; i < cnt; i += 256) csr[base + i] = stg[i];
    } else {  // statistically unreachable fallback
        for (int i = t; i < cnt; i += 256) {
            unsigned v = ebuf[base + i];
            int r = atomicAdd(&sc[v & 127], 1);
            csr[base + r] = (int)(v >> 7);
        }
    }
}

// ---------------- gather 1: aggb[n] = sum Xb[src] (bf16 in, fp32 acc, bf16 out) ----
__global__ __launch_bounds__(256) void gather1(
    const uint2* __restrict__ Xb, const int* __restrict__ off,
    const int* __restrict__ deg, const int* __restrict__ csr,
    uint2* __restrict__ aggb) {
    int t = threadIdx.x, lane = t & 63, wid = t >> 6;
    int il = lane & 15, g = lane >> 4;
    int w0 = blockIdx.x * 4 + wid, stride = gridDim.x * 4;
    for (int n = w0; n < N_NODES; n += stride) {
        int s0 = off[n], d = deg[n];
        float ax = 0.f, ay = 0.f, az = 0.f, aw = 0.f;
        int j = g;
        for (; j + 12 < d; j += 16) {
            int sa = csr[s0 + j], sb = csr[s0 + j + 4];
            int sc = csr[s0 + j + 8], sd = csr[s0 + j + 12];
            uint2 va = Xb[sa * 16 + il], vb = Xb[sb * 16 + il];
            uint2 vc = Xb[sc * 16 + il], vd = Xb[sd * 16 + il];
            ax += bl(va.x) + bl(vb.x) + bl(vc.x) + bl(vd.x);
            ay += bh(va.x) + bh(vb.x) + bh(vc.x) + bh(vd.x);
            az += bl(va.y) + bl(vb.y) + bl(vc.y) + bl(vd.y);
            aw += bh(va.y) + bh(vb.y) + bh(vc.y) + bh(vd.y);
        }
        for (; j < d; j += 4) {
            int sa = csr[s0 + j];
            uint2 va = Xb[sa * 16 + il];
            ax += bl(va.x); ay += bh(va.x); az += bl(va.y); aw += bh(va.y);
        }
#pragma unroll
        for (int m = 16; m < 64; m <<= 1) {
            ax += __shfl_xor(ax, m); ay += __shfl_xor(ay, m);
            az += __shfl_xor(az, m); aw += __shfl_xor(aw, m);
        }
        if (g == 0) {
            uint2 o; o.x = pk2(ax, ay); o.y = pk2(az, aw);
            aggb[n * 16 + il] = o;
        }
    }
}

// ---------------- gemm12: Zb = relu(aggb @ W1 + b1) @ W2  (MFMA, bf16) --------
__global__ __launch_bounds__(256) void gemm12(
    const unsigned short* __restrict__ aggb,
    const float* __restrict__ W1, const float* __restrict__ b1,
    const float* __restrict__ W2,
    unsigned short* __restrict__ Zb) {
    __shared__ unsigned short sW1t[64 * YP];
    __shared__ unsigned short sW2t[32 * YP];
    __shared__ unsigned short sy[4][16 * YP];
    int t = threadIdx.x;
    for (int i = t; i < 64 * 64; i += 256) {
        int k = i >> 6, h = i & 63;
        sW1t[h * YP + k] = bf16r(W1[k * 64 + h]);
    }
    for (int i = t; i < 64 * 32; i += 256) {
        int k = i >> 5, oc = i & 31;
        sW2t[oc * YP + k] = bf16r(W2[k * 32 + oc]);
    }
    __syncthreads();
    int lane = t & 63, wid = t >> 6;
    int m = lane & 15, quad = lane >> 4;
    bhalf8 A1[4][2], A2[2][2];
#pragma unroll
    for (int tile = 0; tile < 4; tile++)
#pragma unroll
        for (int c = 0; c < 2; c++)
            A1[tile][c] = *(const bhalf8*)&sW1t[(tile * 16 + m) * YP + c * 32 + quad * 8];
#pragma unroll
    for (int tile = 0; tile < 2; tile++)
#pragma unroll
        for (int c = 0; c < 2; c++)
            A2[tile][c] = *(const bhalf8*)&sW2t[(tile * 16 + m) * YP + c * 32 + quad * 8];
    f32x4 bias1[4];
#pragma unroll
    for (int tile = 0; tile < 4; tile++)
#pragma unroll
        for (int r = 0; r < 4; r++) bias1[tile][r] = b1[tile * 16 + quad * 4 + r];

    unsigned short* yt = sy[wid];
    int nb0 = blockIdx.x * 4 + wid, nstride = gridDim.x * 4;
    for (int nb = nb0; nb < N_NODES / 16; nb += nstride) {
        int node = nb * 16 + m;
        const unsigned short* arow = aggb + (size_t)node * 64;
        bhalf8 Bc0 = *(const bhalf8*)(arow + quad * 8);
        bhalf8 Bc1 = *(const bhalf8*)(arow + 32 + quad * 8);
#pragma unroll
        for (int tile = 0; tile < 4; tile++) {
            f32x4 a = bias1[tile];
            a = __builtin_amdgcn_mfma_f32_16x16x32_bf16(A1[tile][0], Bc0, a, 0, 0, 0);
            a = __builtin_amdgcn_mfma_f32_16x16x32_bf16(A1[tile][1], Bc1, a, 0, 0, 0);
            float y0 = a[0] > 0.f ? a[0] : 0.f, y1 = a[1] > 0.f ? a[1] : 0.f;
            float y2 = a[2] > 0.f ? a[2] : 0.f, y3 = a[3] > 0.f ? a[3] : 0.f;
            uint2 o; o.x = pk2(y0, y1); o.y = pk2(y2, y3);
            *(uint2*)&yt[m * YP + tile * 16 + quad * 4] = o;
        }
        bhalf8 Y0 = *(const bhalf8*)&yt[m * YP + quad * 8];
        bhalf8 Y1 = *(const bhalf8*)&yt[m * YP + 32 + quad * 8];
#pragma unroll
        for (int tile = 0; tile < 2; tile++) {
            f32x4 z = {0.f, 0.f, 0.f, 0.f};
            z = __builtin_amdgcn_mfma_f32_16x16x32_bf16(A2[tile][0], Y0, z, 0, 0, 0);
            z = __builtin_amdgcn_mfma_f32_16x16x32_bf16(A2[tile][1], Y1, z, 0, 0, 0);
            uint2 o; o.x = pk2(z[0], z[1]); o.y = pk2(z[2], z[3]);
            *(uint2*)&Zb[(size_t)node * 32 + tile * 16 + quad * 4] = o;
        }
    }
}

// ---------------- gather 2: out[n] = sum Zb[src] + b2 (fp32 out) ----------------
__global__ __launch_bounds__(256) void gather2(
    const unsigned* __restrict__ Zb, const int* __restrict__ off,
    const int* __restrict__ deg, const int* __restrict__ csr,
    const float* __restrict__ b2, float2* __restrict__ out) {
    int t = threadIdx.x, lane = t & 63, wid = t >> 6;
    int il = lane & 15, g = lane >> 4;
    float2 bb = ((const float2*)b2)[il];
    int w0 = blockIdx.x * 4 + wid, stride = gridDim.x * 4;
    for (int n = w0; n < N_NODES; n += stride) {
        int s0 = off[n], d = deg[n];
        float ax = 0.f, ay = 0.f;
        int j = g;
        for (; j + 12 < d; j += 16) {
            int sa = csr[s0 + j], sb = csr[s0 + j + 4];
            int sc = csr[s0 + j + 8], sd = csr[s0 + j + 12];
            unsigned ua = Zb[sa * 16 + il], ub = Zb[sb * 16 + il];
            unsigned uc = Zb[sc * 16 + il], ud = Zb[sd * 16 + il];
            ax += bl(ua) + bl(ub) + bl(uc) + bl(ud);
            ay += bh(ua) + bh(ub) + bh(uc) + bh(ud);
        }
        for (; j < d; j += 4) {
            int sa = csr[s0 + j];
            unsigned ua = Zb[sa * 16 + il];
            ax += bl(ua); ay += bh(ua);
        }
#pragma unroll
        for (int m = 16; m < 64; m <<= 1) {
            ax += __shfl_xor(ax, m); ay += __shfl_xor(ay, m);
        }
        if (g == 0) {
            float2 o; o.x = ax + bb.x; o.y = ay + bb.y;
            out[n * 16 + il] = o;
        }
    }
}

extern "C" void kernel_launch(void* const* d_in, const int* in_sizes, int n_in,
                              void* d_out, int out_size, void* d_ws, size_t ws_size,
                              hipStream_t stream) {
    const float* features = (const float*)d_in[0];
    const int*   src      = (const int*)d_in[1];
    const int*   dst      = (const int*)d_in[2];
    const float* W1       = (const float*)d_in[3];
    const float* b1       = (const float*)d_in[4];
    const float* W2       = (const float*)d_in[5];
    const float* b2       = (const float*)d_in[6];

    char* p = (char*)d_ws;
    int* btot  = (int*)p;      p += 1024 * 4;
    int* bbase = (int*)p;      p += 1024 * 4;
    int* gcur  = (int*)p;      p += 1024 * 4;
    int* off   = (int*)p;      p += ((size_t)N_NODES * 4 + 255) / 256 * 256;
    int* deg   = (int*)p;      p += ((size_t)N_NODES * 4 + 255) / 256 * 256;
    unsigned* ebuf = (unsigned*)p; p += (size_t)N_EDGES * 4;
    int* csr   = (int*)p;      p += (size_t)N_EDGES * 4;
    uint2* Xb  = (uint2*)p;    p += (size_t)N_NODES * 64 * 2;
    unsigned short* aggb = (unsigned short*)p; p += (size_t)N_NODES * 64 * 2;
    unsigned short* Zb   = (unsigned short*)p; p += (size_t)N_NODES * 32 * 2;

    convert_zero<<<(N_NODES * 16 + 255) / 256, 256, 0, stream>>>((const float4*)features, Xb, btot);
    pass0<<<(N_EDGES + 4095) / 4096, 256, 0, stream>>>(dst, btot);
    scanB<<<1, 256, 0, stream>>>(btot, bbase, gcur);
    pass1<<<(N_EDGES + 4095) / 4096, 256, 0, stream>>>(src, dst, gcur, ebuf);
    pass2<<<NB, 256, 0, stream>>>(ebuf, bbase, off, deg, csr);

    gather1<<<2048, 256, 0, stream>>>(Xb, off, deg, csr, (uint2*)aggb);
    gemm12<<<256, 256, 0, stream>>>(aggb, W1, b1, W2, Zb);
    gather2<<<2048, 256, 0, stream>>>((const unsigned*)Zb, off, deg, csr, b2, (float2*)d_out);
}

// Round 6
// 200.156 us; speedup vs baseline: 10.8502x; 1.0898x over previous
//
#include <hip/hip_runtime.h>

#define N_NODES 100000
#define N_EDGES 1600000
#define NB 782    // ceil(N_NODES/128) buckets of 128 dst-nodes
#define CAP 3072  // strip capacity per bucket (mean 2046, sigma 45 -> 22-sigma safe)
#define YP 72     // padded LDS row (bf16 elems) for gemm12

typedef __attribute__((ext_vector_type(8))) short bhalf8;
typedef __attribute__((ext_vector_type(4))) float f32x4;

__device__ __forceinline__ unsigned short bf16r(float f) {
    unsigned u = __float_as_uint(f);
    unsigned r = (u >> 16) & 1;
    return (unsigned short)((u + 0x7fffu + r) >> 16);
}
__device__ __forceinline__ unsigned pk2(float a, float b) {
    return (unsigned)bf16r(a) | ((unsigned)bf16r(b) << 16);
}
__device__ __forceinline__ float bl(unsigned u) { return __uint_as_float(u << 16); }
__device__ __forceinline__ float bh(unsigned u) { return __uint_as_float(u & 0xffff0000u); }

// ---------------- prepass: features -> bf16, init strip cursors ----------------
__global__ void convert_zero(const float4* __restrict__ X4, uint2* __restrict__ Xb,
                             int* __restrict__ gcur) {
    int i = blockIdx.x * 256 + threadIdx.x;
    if (i < N_NODES * 16) {
        float4 v = X4[i];
        uint2 o; o.x = pk2(v.x, v.y); o.y = pk2(v.z, v.w);
        Xb[i] = o;
    }
    if (i < NB) gcur[i] = i * CAP;
}

// ---------------- pass1: scatter packed (src<<7|dstlocal) into bucket strips ----
__global__ __launch_bounds__(256) void pass1(const int* __restrict__ src,
                                             const int* __restrict__ dst,
                                             int* __restrict__ gcur,
                                             unsigned* __restrict__ ebuf) {
    __shared__ int h[NB];
    __shared__ int cur[NB];
    int t = threadIdx.x;
    for (int b = t; b < NB; b += 256) h[b] = 0;
    __syncthreads();
    int e0 = blockIdx.x * 4096 + t;
    unsigned pk[16]; int bk[16];
#pragma unroll
    for (int i = 0; i < 16; i++) {
        int e = e0 + i * 256;
        if (e < N_EDGES) {
            int s = src[e], d = dst[e];
            bk[i] = d >> 7;
            pk[i] = ((unsigned)s << 7) | (unsigned)(d & 127);
            atomicAdd(&h[bk[i]], 1);
        } else bk[i] = -1;
    }
    __syncthreads();
    for (int b = t; b < NB; b += 256)
        cur[b] = h[b] ? atomicAdd(&gcur[b], h[b]) : 0;
    __syncthreads();
#pragma unroll
    for (int i = 0; i < 16; i++)
        if (bk[i] >= 0) {
            int r = atomicAdd(&cur[bk[i]], 1);
            ebuf[r] = pk[i];
        }
}

// ---------------- pass2: per-bucket node offsets + coalesced CSR write ----------
__global__ __launch_bounds__(256) void pass2(const unsigned* __restrict__ ebuf,
                                             const int* __restrict__ gcur,
                                             int* __restrict__ off,
                                             int* __restrict__ deg,
                                             int* __restrict__ csr) {
    __shared__ int hh[128], sc[128];
    __shared__ int stg[CAP];
    int b = blockIdx.x, t = threadIdx.x;
    int base = b * CAP, cnt = gcur[b] - base;
    if (t < 128) hh[t] = 0;
    __syncthreads();
    for (int i = t; i < cnt; i += 256) atomicAdd(&hh[ebuf[base + i] & 127], 1);
    __syncthreads();
    if (t == 0) { int a = 0; for (int k = 0; k < 128; k++) { sc[k] = a; a += hh[k]; } }
    __syncthreads();
    if (t < 128) {
        int n = b * 128 + t;
        if (n < N_NODES) { off[n] = base + sc[t]; deg[n] = hh[t]; }
    }
    __syncthreads();
    for (int i = t; i < cnt; i += 256) {
        unsigned v = ebuf[base + i];
        int r = atomicAdd(&sc[v & 127], 1);
        stg[r] = (int)(v >> 7);
    }
    __syncthreads();
    for (int i = t; i < cnt; i += 256) csr[base + i] = stg[i];
}

// ---------------- gather 1: aggb[n] = sum Xb[src] -----------------------------
// 8 lanes/row via uint4 (16 B); 8 groups x unroll 2 -> 16 rows in flight/wave.
__global__ __launch_bounds__(256) void gather1(
    const uint4* __restrict__ Xb4, const int* __restrict__ off,
    const int* __restrict__ deg, const int* __restrict__ csr,
    uint4* __restrict__ aggb4) {
    int t = threadIdx.x, lane = t & 63, wid = t >> 6;
    int il = lane & 7, g = lane >> 3;
    int w0 = blockIdx.x * 4 + wid, stride = gridDim.x * 4;
    for (int n = w0; n < N_NODES; n += stride) {
        int s0 = off[n], d = deg[n];
        float a0 = 0.f, a1 = 0.f, a2 = 0.f, a3 = 0.f;
        float a4 = 0.f, a5 = 0.f, a6 = 0.f, a7 = 0.f;
        int j = g;
        for (; j + 8 < d; j += 16) {
            int sa = csr[s0 + j], sb = csr[s0 + j + 8];
            uint4 va = Xb4[sa * 8 + il], vb = Xb4[sb * 8 + il];
            a0 += bl(va.x) + bl(vb.x); a1 += bh(va.x) + bh(vb.x);
            a2 += bl(va.y) + bl(vb.y); a3 += bh(va.y) + bh(vb.y);
            a4 += bl(va.z) + bl(vb.z); a5 += bh(va.z) + bh(vb.z);
            a6 += bl(va.w) + bl(vb.w); a7 += bh(va.w) + bh(vb.w);
        }
        if (j < d) {
            int sa = csr[s0 + j];
            uint4 va = Xb4[sa * 8 + il];
            a0 += bl(va.x); a1 += bh(va.x); a2 += bl(va.y); a3 += bh(va.y);
            a4 += bl(va.z); a5 += bh(va.z); a6 += bl(va.w); a7 += bh(va.w);
        }
#pragma unroll
        for (int m = 8; m < 64; m <<= 1) {
            a0 += __shfl_xor(a0, m); a1 += __shfl_xor(a1, m);
            a2 += __shfl_xor(a2, m); a3 += __shfl_xor(a3, m);
            a4 += __shfl_xor(a4, m); a5 += __shfl_xor(a5, m);
            a6 += __shfl_xor(a6, m); a7 += __shfl_xor(a7, m);
        }
        if (g == 0) {
            uint4 o;
            o.x = pk2(a0, a1); o.y = pk2(a2, a3);
            o.z = pk2(a4, a5); o.w = pk2(a6, a7);
            aggb4[n * 8 + il] = o;
        }
    }
}

// ---------------- gemm12: Zb = relu(aggb @ W1 + b1) @ W2  (MFMA, bf16) --------
__global__ __launch_bounds__(256) void gemm12(
    const unsigned short* __restrict__ aggb,
    const float* __restrict__ W1, const float* __restrict__ b1,
    const float* __restrict__ W2,
    unsigned short* __restrict__ Zb) {
    __shared__ unsigned short sW1t[64 * YP];
    __shared__ unsigned short sW2t[32 * YP];
    __shared__ unsigned short sy[4][16 * YP];
    int t = threadIdx.x;
    for (int i = t; i < 64 * 64; i += 256) {
        int k = i >> 6, h = i & 63;
        sW1t[h * YP + k] = bf16r(W1[k * 64 + h]);
    }
    for (int i = t; i < 64 * 32; i += 256) {
        int k = i >> 5, oc = i & 31;
        sW2t[oc * YP + k] = bf16r(W2[k * 32 + oc]);
    }
    __syncthreads();
    int lane = t & 63, wid = t >> 6;
    int m = lane & 15, quad = lane >> 4;
    bhalf8 A1[4][2], A2[2][2];
#pragma unroll
    for (int tile = 0; tile < 4; tile++)
#pragma unroll
        for (int c = 0; c < 2; c++)
            A1[tile][c] = *(const bhalf8*)&sW1t[(tile * 16 + m) * YP + c * 32 + quad * 8];
#pragma unroll
    for (int tile = 0; tile < 2; tile++)
#pragma unroll
        for (int c = 0; c < 2; c++)
            A2[tile][c] = *(const bhalf8*)&sW2t[(tile * 16 + m) * YP + c * 32 + quad * 8];
    f32x4 bias1[4];
#pragma unroll
    for (int tile = 0; tile < 4; tile++)
#pragma unroll
        for (int r = 0; r < 4; r++) bias1[tile][r] = b1[tile * 16 + quad * 4 + r];

    unsigned short* yt = sy[wid];
    int nb0 = blockIdx.x * 4 + wid, nstride = gridDim.x * 4;
    for (int nb = nb0; nb < N_NODES / 16; nb += nstride) {
        int node = nb * 16 + m;
        const unsigned short* arow = aggb + (size_t)node * 64;
        bhalf8 Bc0 = *(const bhalf8*)(arow + quad * 8);
        bhalf8 Bc1 = *(const bhalf8*)(arow + 32 + quad * 8);
#pragma unroll
        for (int tile = 0; tile < 4; tile++) {
            f32x4 a = bias1[tile];
            a = __builtin_amdgcn_mfma_f32_16x16x32_bf16(A1[tile][0], Bc0, a, 0, 0, 0);
            a = __builtin_amdgcn_mfma_f32_16x16x32_bf16(A1[tile][1], Bc1, a, 0, 0, 0);
            float y0 = a[0] > 0.f ? a[0] : 0.f, y1 = a[1] > 0.f ? a[1] : 0.f;
            float y2 = a[2] > 0.f ? a[2] : 0.f, y3 = a[3] > 0.f ? a[3] : 0.f;
            uint2 o; o.x = pk2(y0, y1); o.y = pk2(y2, y3);
            *(uint2*)&yt[m * YP + tile * 16 + quad * 4] = o;
        }
        bhalf8 Y0 = *(const bhalf8*)&yt[m * YP + quad * 8];
        bhalf8 Y1 = *(const bhalf8*)&yt[m * YP + 32 + quad * 8];
#pragma unroll
        for (int tile = 0; tile < 2; tile++) {
            f32x4 z = {0.f, 0.f, 0.f, 0.f};
            z = __builtin_amdgcn_mfma_f32_16x16x32_bf16(A2[tile][0], Y0, z, 0, 0, 0);
            z = __builtin_amdgcn_mfma_f32_16x16x32_bf16(A2[tile][1], Y1, z, 0, 0, 0);
            uint2 o; o.x = pk2(z[0], z[1]); o.y = pk2(z[2], z[3]);
            *(uint2*)&Zb[(size_t)node * 32 + tile * 16 + quad * 4] = o;
        }
    }
}

// ---------------- gather 2: out[n] = sum Zb[src] + b2 (fp32 out) ----------------
// 8 lanes/row via uint2 (8 B); 8 groups x unroll 2 -> 16 rows in flight/wave.
__global__ __launch_bounds__(256) void gather2(
    const uint2* __restrict__ Zb2, const int* __restrict__ off,
    const int* __restrict__ deg, const int* __restrict__ csr,
    const float* __restrict__ b2, float4* __restrict__ out4) {
    int t = threadIdx.x, lane = t & 63, wid = t >> 6;
    int il = lane & 7, g = lane >> 3;
    float4 bb = ((const float4*)b2)[il];
    int w0 = blockIdx.x * 4 + wid, stride = gridDim.x * 4;
    for (int n = w0; n < N_NODES; n += stride) {
        int s0 = off[n], d = deg[n];
        float a0 = 0.f, a1 = 0.f, a2 = 0.f, a3 = 0.f;
        int j = g;
        for (; j + 8 < d; j += 16) {
            int sa = csr[s0 + j], sb = csr[s0 + j + 8];
            uint2 va = Zb2[sa * 8 + il], vb = Zb2[sb * 8 + il];
            a0 += bl(va.x) + bl(vb.x); a1 += bh(va.x) + bh(vb.x);
            a2 += bl(va.y) + bl(vb.y); a3 += bh(va.y) + bh(vb.y);
        }
        if (j < d) {
            int sa = csr[s0 + j];
            uint2 va = Zb2[sa * 8 + il];
            a0 += bl(va.x); a1 += bh(va.x); a2 += bl(va.y); a3 += bh(va.y);
        }
#pragma unroll
        for (int m = 8; m < 64; m <<= 1) {
            a0 += __shfl_xor(a0, m); a1 += __shfl_xor(a1, m);
            a2 += __shfl_xor(a2, m); a3 += __shfl_xor(a3, m);
        }
        if (g == 0) {
            float4 o;
            o.x = a0 + bb.x; o.y = a1 + bb.y; o.z = a2 + bb.z; o.w = a3 + bb.w;
            out4[n * 8 + il] = o;
        }
    }
}

extern "C" void kernel_launch(void* const* d_in, const int* in_sizes, int n_in,
                              void* d_out, int out_size, void* d_ws, size_t ws_size,
                              hipStream_t stream) {
    const float* features = (const float*)d_in[0];
    const int*   src      = (const int*)d_in[1];
    const int*   dst      = (const int*)d_in[2];
    const float* W1       = (const float*)d_in[3];
    const float* b1       = (const float*)d_in[4];
    const float* W2       = (const float*)d_in[5];
    const float* b2       = (const float*)d_in[6];

    char* p = (char*)d_ws;
    int* gcur = (int*)p;       p += 1024 * 4;
    int* off  = (int*)p;       p += ((size_t)N_NODES * 4 + 255) / 256 * 256;
    int* deg  = (int*)p;       p += ((size_t)N_NODES * 4 + 255) / 256 * 256;
    unsigned* ebuf = (unsigned*)p; p += (size_t)NB * CAP * 4;
    int* csr  = (int*)p;       p += (size_t)NB * CAP * 4;
    uint2* Xb = (uint2*)p;     p += (size_t)N_NODES * 64 * 2;
    unsigned short* aggb = (unsigned short*)p; p += (size_t)N_NODES * 64 * 2;
    unsigned short* Zb   = (unsigned short*)p; p += (size_t)N_NODES * 32 * 2;

    convert_zero<<<(N_NODES * 16 + 255) / 256, 256, 0, stream>>>((const float4*)features, Xb, gcur);
    pass1<<<(N_EDGES + 4095) / 4096, 256, 0, stream>>>(src, dst, gcur, ebuf);
    pass2<<<NB, 256, 0, stream>>>(ebuf, gcur, off, deg, csr);

    gather1<<<2048, 256, 0, stream>>>((const uint4*)Xb, off, deg, csr, (uint4*)aggb);
    gemm12<<<256, 256, 0, stream>>>(aggb, W1, b1, W2, Zb);
    gather2<<<2048, 256, 0, stream>>>((const uint2*)Zb, off, deg, csr, b2, (float4*)d_out);
}